// Round 1
// baseline (9020.586 us; speedup 1.0000x reference)
//
#include <hip/hip_runtime.h>

typedef unsigned short u16;
typedef __attribute__((ext_vector_type(4))) unsigned short u16x4;
typedef __attribute__((ext_vector_type(8))) unsigned short u16x8;
typedef __attribute__((ext_vector_type(8))) __bf16 bf16x8;
typedef __attribute__((ext_vector_type(4))) float f32x4;

#define N_BANK  50000
#define NPAD    50048      // 782 * 64
#define NCHUNKS 782
#define SEGS    32
#define DIM     128
#define NQ      4096

// ---- workspace layout (byte offsets, all 256B-aligned; total ~16.7 MB) ----
#define WS_BANKBF 0u          // NPAD*128*2  = 12,812,288
#define WS_B2     12812288u   // NPAD*4      =    200,192
#define WS_QBF    13012480u   // 4096*128*2  =  1,048,576
#define WS_Q2     14061056u   // 4096*4      =     16,384
#define WS_SEGD   14077440u   // 4096*32*5*4 =  2,621,440
#define WS_SCORES 16698880u   // 4096*4      =     16,384

__device__ __forceinline__ u16 f2bf(float f) {
  unsigned int x = __float_as_uint(f);
  x += 0x7fffu + ((x >> 16) & 1u);   // RNE to bf16
  return (u16)(x >> 16);
}

// precondition: x < T[4]; keeps T[0..4] sorted ascending
__device__ __forceinline__ void insert5(float* T, float x) {
  bool c3 = x < T[3], c2 = x < T[2], c1 = x < T[1], c0 = x < T[0];
  T[4] = c3 ? T[3] : x;
  T[3] = c3 ? (c2 ? T[2] : x) : T[3];
  T[2] = c2 ? (c1 ? T[1] : x) : T[2];
  T[1] = c1 ? (c0 ? T[0] : x) : T[1];
  T[0] = c0 ? x : T[0];
}

__device__ __forceinline__ void gload_lds16(const void* g, void* l) {
  __builtin_amdgcn_global_load_lds(
      (const __attribute__((address_space(1))) void*)g,
      (__attribute__((address_space(3))) void*)l, 16, 0, 0);
}

// ---------- prep: bank -> bf16 (+ pad rows), b2 = ||b||^2 (pad = 1e30) ----------
__global__ __launch_bounds__(256) void prep_bank(const float* __restrict__ bank,
                                                 u16* __restrict__ bb,
                                                 float* __restrict__ b2) {
  int row = blockIdx.x * 8 + (threadIdx.x >> 5);   // 6256 blocks -> 50048 rows
  int cc  = threadIdx.x & 31;                      // 32 lanes * 4 floats = 128
  bool valid = row < N_BANK;
  f32x4 v = f32x4{0.f, 0.f, 0.f, 0.f};
  if (valid) v = *reinterpret_cast<const f32x4*>(bank + (size_t)row * DIM + cc * 4);
  float s = v.x * v.x + v.y * v.y + v.z * v.z + v.w * v.w;
#pragma unroll
  for (int o = 16; o > 0; o >>= 1) s += __shfl_xor(s, o, 32);
  u16x4 u;
  u.x = f2bf(v.x); u.y = f2bf(v.y); u.z = f2bf(v.z); u.w = f2bf(v.w);
  *reinterpret_cast<u16x4*>(bb + (size_t)row * DIM + cc * 4) = u;
  if (cc == 0) b2[row] = valid ? s : 1e30f;
}

// ---------- prep: embeddings [4,128,32,32] -> q_bf16 [4096][128], q2 ----------
__global__ __launch_bounds__(256) void prep_q(const float* __restrict__ emb,
                                              u16* __restrict__ qb,
                                              float* __restrict__ q2) {
  int q = blockIdx.x * 256 + threadIdx.x;          // 16 blocks -> 4096
  int b = q >> 10, yx = q & 1023;
  const float* src = emb + (size_t)b * 131072 + yx; // stride 1024 over d
  float s = 0.f;
#pragma unroll
  for (int d0 = 0; d0 < 16; ++d0) {
    u16x8 u;
#pragma unroll
    for (int j = 0; j < 8; ++j) {
      float v = src[(d0 * 8 + j) * 1024];
      s += v * v;
      u[j] = f2bf(v);
    }
    *reinterpret_cast<u16x8*>(qb + (size_t)q * DIM + d0 * 8) = u;
  }
  q2[q] = s;
}

// ---------- main fused GEMM + per-query top-5 (per bank segment) ----------
// grid 512 = 16 query-groups (256 q each) x 32 segments. block = 4 waves.
// wave owns 64 queries (B-frags in regs); 64-row bank chunks staged in LDS.
__global__ __launch_bounds__(256) void knn_kernel(const u16* __restrict__ bankbf,
                                                  const float* __restrict__ b2,
                                                  const u16* __restrict__ qbf,
                                                  float* __restrict__ segd) {
  __shared__ float smem[5120];       // 20KB: first 16KB = chunk buf; all = merge buf
  char* smc = (char*)smem;
  const int tid = threadIdx.x;
  const int w   = tid >> 6;
  const int l   = tid & 63;
  const int l15 = l & 15, lhi = l >> 4;
  const int qgi = blockIdx.x & 15;
  const int seg = blockIdx.x >> 4;
  const int qbase = qgi * 256 + w * 64;

  // B fragments: 4 query-subgroups x 4 K-chunks, register-resident all kernel
  bf16x8 bq[16];
#pragma unroll
  for (int qg = 0; qg < 4; ++qg)
#pragma unroll
    for (int kk = 0; kk < 4; ++kk)
      bq[qg * 4 + kk] = *reinterpret_cast<const bf16x8*>(
          qbf + (size_t)(qbase + qg * 16 + l15) * DIM + kk * 32 + lhi * 8);

  float t5[20];                       // 4 subgroups x sorted top-5 of (b2 - 2*dot)
#pragma unroll
  for (int i = 0; i < 20; ++i) t5[i] = 3e38f;

  for (int c = seg; c < NCHUNKS; c += SEGS) {
    const char* gbase = (const char*)bankbf + (size_t)c * 16384;
    // stage 64x128 bf16 chunk; LDS dest linear, XOR-swizzle applied to SOURCE
#pragma unroll
    for (int i = 0; i < 4; ++i) {
      int x  = w * 4096 + i * 1024 + l * 16;
      int sx = x ^ (((x >> 8) & 7) << 4);
      gload_lds16(gbase + sx, smc + w * 4096 + i * 1024);
    }
    __syncthreads();
    const int rowbase = c * 64;
#pragma unroll
    for (int t = 0; t < 4; ++t) {
      f32x4 b2v = *reinterpret_cast<const f32x4*>(b2 + rowbase + t * 16 + lhi * 4);
      bf16x8 af[4];
#pragma unroll
      for (int kk = 0; kk < 4; ++kk) {
        int p  = (t * 16 + l15) * 256 + kk * 64 + lhi * 16;
        int ph = p ^ (((p >> 8) & 7) << 4);   // swizzled read
        af[kk] = *reinterpret_cast<const bf16x8*>(smc + ph);
      }
      f32x4 acc[4];
#pragma unroll
      for (int qg = 0; qg < 4; ++qg) acc[qg] = f32x4{0.f, 0.f, 0.f, 0.f};
#pragma unroll
      for (int kk = 0; kk < 4; ++kk)
#pragma unroll
        for (int qg = 0; qg < 4; ++qg)
          acc[qg] = __builtin_amdgcn_mfma_f32_16x16x32_bf16(af[kk], bq[qg * 4 + kk],
                                                            acc[qg], 0, 0, 0);
#pragma unroll
      for (int qg = 0; qg < 4; ++qg) {
#pragma unroll
        for (int j = 0; j < 4; ++j) {
          float d2 = fmaf(-2.f, acc[qg][j], b2v[j]);   // b2 - 2*dot (q2 added later)
          if (d2 < t5[qg * 5 + 4]) insert5(t5 + qg * 5, d2);
        }
      }
    }
    __syncthreads();
  }

  // merge the 4 lane-groups' top-5 per query, emit per-segment top-5
#pragma unroll
  for (int qg = 0; qg < 4; ++qg)
#pragma unroll
    for (int j = 0; j < 5; ++j)
      smem[((w * 4 + qg) * 16 + l15) * 20 + lhi * 5 + j] = t5[qg * 5 + j];
  __syncthreads();
  {
    int w2 = tid >> 6, qg2 = (tid >> 4) & 3, cc = tid & 15;
    const float* S = smem + ((w2 * 4 + qg2) * 16 + cc) * 20;
    float best[5] = {3e38f, 3e38f, 3e38f, 3e38f, 3e38f};
    for (int i = 0; i < 20; ++i) {
      float x = S[i];
      if (x < best[4]) insert5(best, x);
    }
    int q = qgi * 256 + w2 * 64 + qg2 * 16 + cc;
    float* dst = segd + (size_t)q * (SEGS * 5) + seg * 5;
#pragma unroll
    for (int j = 0; j < 5; ++j) dst[j] = best[j];
  }
}

// ---------- merge segments, add q2, sqrt, mean ----------
__global__ __launch_bounds__(256) void final_merge(const float* __restrict__ segd,
                                                   const float* __restrict__ q2,
                                                   float* __restrict__ scores) {
  int q = blockIdx.x * 256 + threadIdx.x;          // 16 blocks -> 4096
  const float* S = segd + (size_t)q * (SEGS * 5);
  float best[5] = {3e38f, 3e38f, 3e38f, 3e38f, 3e38f};
  for (int i = 0; i < SEGS * 5; ++i) {
    float x = S[i];
    if (x < best[4]) insert5(best, x);
  }
  float q2v = q2[q];
  float s = 0.f;
#pragma unroll
  for (int j = 0; j < 5; ++j) s += sqrtf(fmaxf(q2v + best[j], 1e-12f));
  scores[q] = s * 0.2f;
}

// ---------- half-pixel bilinear 32x32 -> 512x512 (clamped == jax renorm) ----------
__global__ __launch_bounds__(256) void resize_kernel(const float* __restrict__ scores,
                                                     float* __restrict__ out) {
  int idx = blockIdx.x * 256 + threadIdx.x;        // 4096 blocks -> 1,048,576
  int b = idx >> 18;
  int rem = idx & 262143;
  int oy = rem >> 9, ox = rem & 511;
  float sx = (ox + 0.5f) * 0.0625f - 0.5f;
  float sy = (oy + 0.5f) * 0.0625f - 0.5f;
  float fx0 = floorf(sx), fy0 = floorf(sy);
  int x0 = (int)fx0, y0 = (int)fy0;
  float fx = sx - fx0, fy = sy - fy0;
  int x0c = x0 < 0 ? 0 : (x0 > 31 ? 31 : x0);
  int x1c = (x0 + 1) < 0 ? 0 : ((x0 + 1) > 31 ? 31 : (x0 + 1));
  int y0c = y0 < 0 ? 0 : (y0 > 31 ? 31 : y0);
  int y1c = (y0 + 1) < 0 ? 0 : ((y0 + 1) > 31 ? 31 : (y0 + 1));
  const float* sb = scores + (b << 10);
  float v00 = sb[y0c * 32 + x0c], v01 = sb[y0c * 32 + x1c];
  float v10 = sb[y1c * 32 + x0c], v11 = sb[y1c * 32 + x1c];
  float v0 = v00 + (v01 - v00) * fx;
  float v1 = v10 + (v11 - v10) * fx;
  out[idx] = v0 + (v1 - v0) * fy;
}

extern "C" void kernel_launch(void* const* d_in, const int* in_sizes, int n_in,
                              void* d_out, int out_size, void* d_ws, size_t ws_size,
                              hipStream_t stream) {
  const float* emb  = (const float*)d_in[0];   // [4,128,32,32]
  const float* bank = (const float*)d_in[1];   // [50000,128]
  float* out = (float*)d_out;                  // [4,1,512,512]
  char* ws = (char*)d_ws;

  u16*   bankbf = (u16*)(ws + WS_BANKBF);
  float* b2     = (float*)(ws + WS_B2);
  u16*   qbf    = (u16*)(ws + WS_QBF);
  float* q2     = (float*)(ws + WS_Q2);
  float* segd   = (float*)(ws + WS_SEGD);
  float* scores = (float*)(ws + WS_SCORES);

  prep_bank<<<NPAD / 8, 256, 0, stream>>>(bank, bankbf, b2);
  prep_q<<<NQ / 256, 256, 0, stream>>>(emb, qbf, q2);
  knn_kernel<<<16 * SEGS, 256, 0, stream>>>(bankbf, b2, qbf, segd);
  final_merge<<<NQ / 256, 256, 0, stream>>>(segd, q2, scores);
  resize_kernel<<<(NQ * 256) / 256, 256, 0, stream>>>(scores, out);
}

// Round 3
// 217.760 us; speedup vs baseline: 41.4243x; 41.4243x over previous
//
#include <hip/hip_runtime.h>

typedef unsigned short u16;
typedef __attribute__((ext_vector_type(4))) unsigned short u16x4;
typedef __attribute__((ext_vector_type(8))) unsigned short u16x8;
typedef __attribute__((ext_vector_type(8))) __bf16 bf16x8;
typedef __attribute__((ext_vector_type(4))) float f32x4;

#define N_BANK  50000
#define NPAD    50048      // 782 * 64
#define NCHUNKS 782        // 64-row chunks
#define SEGS    32
#define DIM     128
#define NQ      4096
#define CHUNK_B 16384      // 64 rows * 128 dims * 2B

// ---- workspace layout (byte offsets, all 256B-aligned; total ~16.7 MB) ----
#define WS_BANKBF 0u          // NPAD*128*2  = 12,812,288
#define WS_B2     12812288u   // NPAD*4      =    200,192
#define WS_QBF    13012480u   // 4096*128*2  =  1,048,576
#define WS_Q2     14061056u   // 4096*4      =     16,384
#define WS_SEGD   14077440u   // 4096*32*5*4 =  2,621,440
#define WS_SCORES 16698880u   // 4096*4      =     16,384

__device__ __forceinline__ u16 f2bf(float f) {
  unsigned int x = __float_as_uint(f);
  x += 0x7fffu + ((x >> 16) & 1u);   // RNE to bf16
  return (u16)(x >> 16);
}

// sorted-ascending top-5 insert on NAMED scalars (guaranteed registers).
// precondition: x < T4.
#define INS5(T0, T1, T2, T3, T4, x)                                   \
  {                                                                   \
    bool c3 = (x) < T3, c2 = (x) < T2, c1 = (x) < T1, c0 = (x) < T0;  \
    T4 = c3 ? T3 : (x);                                               \
    T3 = c3 ? (c2 ? T2 : (x)) : T3;                                   \
    T2 = c2 ? (c1 ? T1 : (x)) : T2;                                   \
    T1 = c1 ? (c0 ? T0 : (x)) : T1;                                   \
    T0 = c0 ? (x) : T0;                                               \
  }

__device__ __forceinline__ void gload_lds16(const void* g, void* l) {
  __builtin_amdgcn_global_load_lds(
      (const __attribute__((address_space(1))) void*)g,
      (__attribute__((address_space(3))) void*)l, 16, 0, 0);
}

// ---------- prep: bank -> bf16 (+ pad rows), b2 = ||b||^2 (pad = 1e30) ----------
__global__ __launch_bounds__(256) void prep_bank(const float* __restrict__ bank,
                                                 u16* __restrict__ bb,
                                                 float* __restrict__ b2) {
  int row = blockIdx.x * 8 + (threadIdx.x >> 5);   // 6256 blocks -> 50048 rows
  int cc  = threadIdx.x & 31;                      // 32 lanes * 4 floats = 128
  bool valid = row < N_BANK;
  f32x4 v = f32x4{0.f, 0.f, 0.f, 0.f};
  if (valid) v = *reinterpret_cast<const f32x4*>(bank + (size_t)row * DIM + cc * 4);
  float s = v.x * v.x + v.y * v.y + v.z * v.z + v.w * v.w;
#pragma unroll
  for (int o = 16; o > 0; o >>= 1) s += __shfl_xor(s, o, 32);
  u16x4 u;
  u.x = f2bf(v.x); u.y = f2bf(v.y); u.z = f2bf(v.z); u.w = f2bf(v.w);
  *reinterpret_cast<u16x4*>(bb + (size_t)row * DIM + cc * 4) = u;
  if (cc == 0) b2[row] = valid ? s : 1e30f;
}

// ---------- prep: embeddings [4,128,32,32] -> q_bf16 [4096][128], q2 ----------
__global__ __launch_bounds__(256) void prep_q(const float* __restrict__ emb,
                                              u16* __restrict__ qb,
                                              float* __restrict__ q2) {
  int q = blockIdx.x * 256 + threadIdx.x;          // 16 blocks -> 4096
  int b = q >> 10, yx = q & 1023;
  const float* src = emb + (size_t)b * 131072 + yx; // stride 1024 over d
  float s = 0.f;
#pragma unroll
  for (int d0 = 0; d0 < 16; ++d0) {
    u16x8 u;
#pragma unroll
    for (int j = 0; j < 8; ++j) {
      float v = src[(d0 * 8 + j) * 1024];
      s += v * v;
      u[j] = f2bf(v);
    }
    *reinterpret_cast<u16x8*>(qb + (size_t)q * DIM + d0 * 8) = u;
  }
  q2[q] = s;
}

// ---------- main fused GEMM + per-query top-5 (per bank segment) ----------
// grid 512 = 16 query-groups (256 q each) x 32 segments. block = 8 waves (512 thr).
// wave owns 32 queries (2 subgroups of 16; B-frags = 32 VGPRs, register-resident).
// 64-row bank chunks double-buffered in LDS (2 x 16KB), XOR-swizzled.
__global__ __launch_bounds__(512) void knn_kernel(const u16* __restrict__ bankbf,
                                                  const float* __restrict__ b2,
                                                  const u16* __restrict__ qbf,
                                                  float* __restrict__ segd) {
  __shared__ float smem[8192];       // 32KB: 2 chunk buffers; reused for merge
  char* smc = (char*)smem;
  const int tid = threadIdx.x;
  const int w   = tid >> 6;          // wave 0..7
  const int l   = tid & 63;
  const int l15 = l & 15, lhi = l >> 4;
  const int qgi = blockIdx.x & 15;
  const int seg = blockIdx.x >> 4;

  // B fragments: 2 query-subgroups x 4 K-chunks, register-resident all kernel
  bf16x8 bqA[4], bqB[4];
  {
    const u16* qa = qbf + (size_t)(qgi * 256 + w * 32 + l15) * DIM + lhi * 8;
#pragma unroll
    for (int kk = 0; kk < 4; ++kk) {
      bqA[kk] = *reinterpret_cast<const bf16x8*>(qa + kk * 32);
      bqB[kk] = *reinterpret_cast<const bf16x8*>(qa + 16 * DIM + kk * 32);
    }
  }

  // top-5 of (b2 - 2*dot) per subgroup, named scalars (sorted ascending)
  float a0 = 3e38f, a1 = 3e38f, a2 = 3e38f, a3 = 3e38f, a4 = 3e38f;
  float e0 = 3e38f, e1 = 3e38f, e2 = 3e38f, e3 = 3e38f, e4 = 3e38f;

  // stage chunk cc into LDS buffer buf (dest linear, XOR-swizzle on SOURCE)
  auto stage = [&](int cc, int buf) {
    const char* gb = (const char*)bankbf + (size_t)cc * CHUNK_B;
#pragma unroll
    for (int i = 0; i < 2; ++i) {
      int x  = i * 8192 + tid * 16;            // = i*8192 + w*1024 + l*16
      int sx = x ^ (((x >> 8) & 7) << 4);
      gload_lds16(gb + sx, smc + buf * CHUNK_B + i * 8192 + w * 1024);
    }
  };

  stage(seg, 0);
  __syncthreads();                   // drains vmcnt: buffer 0 ready
  int cur = 0;

  for (int c = seg; c < NCHUNKS; c += SEGS) {
    int cn = c + SEGS;
    if (cn < NCHUNKS) stage(cn, cur ^ 1);      // prefetch next chunk
    const int rowbase = c * 64;
#pragma unroll
    for (int t = 0; t < 4; ++t) {
      f32x4 b2v = *reinterpret_cast<const f32x4*>(b2 + rowbase + t * 16 + lhi * 4);
      bf16x8 af[4];
#pragma unroll
      for (int kk = 0; kk < 4; ++kk) {
        int p  = (t * 16 + l15) * 256 + kk * 64 + lhi * 16;
        int ph = p ^ (((p >> 8) & 7) << 4);    // swizzled read
        af[kk] = *reinterpret_cast<const bf16x8*>(smc + cur * CHUNK_B + ph);
      }
      f32x4 accA = f32x4{0.f, 0.f, 0.f, 0.f};
      f32x4 accB = f32x4{0.f, 0.f, 0.f, 0.f};
#pragma unroll
      for (int kk = 0; kk < 4; ++kk) {
        accA = __builtin_amdgcn_mfma_f32_16x16x32_bf16(af[kk], bqA[kk], accA, 0, 0, 0);
        accB = __builtin_amdgcn_mfma_f32_16x16x32_bf16(af[kk], bqB[kk], accB, 0, 0, 0);
      }
#pragma unroll
      for (int j = 0; j < 4; ++j) {
        float dA = fmaf(-2.f, accA[j], b2v[j]);   // b2 - 2*dot (q2 added later)
        if (dA < a4) INS5(a0, a1, a2, a3, a4, dA);
        float dB = fmaf(-2.f, accB[j], b2v[j]);
        if (dB < e4) INS5(e0, e1, e2, e3, e4, dB);
      }
    }
    __syncthreads();                 // all reads of cur done; next buffer ready
    cur ^= 1;
  }

  // merge the 4 lane-groups' top-5 per query, emit per-segment top-5.
  // local query index qq = w*32 + sg*16 + l15 in [0,256); 20 floats per query.
  {
    float* dstA = smem + (w * 32 + l15) * 20 + lhi * 5;
    dstA[0] = a0; dstA[1] = a1; dstA[2] = a2; dstA[3] = a3; dstA[4] = a4;
    float* dstB = smem + (w * 32 + 16 + l15) * 20 + lhi * 5;
    dstB[0] = e0; dstB[1] = e1; dstB[2] = e2; dstB[3] = e3; dstB[4] = e4;
  }
  __syncthreads();
  if (tid < 256) {
    const float* S = smem + tid * 20;
    float b0 = 3e38f, b1 = 3e38f, b2_ = 3e38f, b3 = 3e38f, b4 = 3e38f;
    for (int i = 0; i < 20; ++i) {
      float x = S[i];
      if (x < b4) INS5(b0, b1, b2_, b3, b4, x);
    }
    float* dst = segd + (size_t)(qgi * 256 + tid) * (SEGS * 5) + seg * 5;
    dst[0] = b0; dst[1] = b1; dst[2] = b2_; dst[3] = b3; dst[4] = b4;
  }
}

// ---------- merge segments, add q2, sqrt, mean ----------
__global__ __launch_bounds__(256) void final_merge(const float* __restrict__ segd,
                                                   const float* __restrict__ q2,
                                                   float* __restrict__ scores) {
  int q = blockIdx.x * 256 + threadIdx.x;          // 16 blocks -> 4096
  const float* S = segd + (size_t)q * (SEGS * 5);
  float b0 = 3e38f, b1 = 3e38f, b2_ = 3e38f, b3 = 3e38f, b4 = 3e38f;
  for (int i = 0; i < SEGS * 5; ++i) {
    float x = S[i];
    if (x < b4) INS5(b0, b1, b2_, b3, b4, x);
  }
  float q2v = q2[q];
  float s = sqrtf(fmaxf(q2v + b0, 1e-12f)) + sqrtf(fmaxf(q2v + b1, 1e-12f)) +
            sqrtf(fmaxf(q2v + b2_, 1e-12f)) + sqrtf(fmaxf(q2v + b3, 1e-12f)) +
            sqrtf(fmaxf(q2v + b4, 1e-12f));
  scores[q] = s * 0.2f;
}

// ---------- half-pixel bilinear 32x32 -> 512x512 (clamped == jax renorm) ----------
__global__ __launch_bounds__(256) void resize_kernel(const float* __restrict__ scores,
                                                     float* __restrict__ out) {
  int idx = blockIdx.x * 256 + threadIdx.x;        // 4096 blocks -> 1,048,576
  int b = idx >> 18;
  int rem = idx & 262143;
  int oy = rem >> 9, ox = rem & 511;
  float sx = (ox + 0.5f) * 0.0625f - 0.5f;
  float sy = (oy + 0.5f) * 0.0625f - 0.5f;
  float fx0 = floorf(sx), fy0 = floorf(sy);
  int x0 = (int)fx0, y0 = (int)fy0;
  float fx = sx - fx0, fy = sy - fy0;
  int x0c = x0 < 0 ? 0 : (x0 > 31 ? 31 : x0);
  int x1c = (x0 + 1) < 0 ? 0 : ((x0 + 1) > 31 ? 31 : (x0 + 1));
  int y0c = y0 < 0 ? 0 : (y0 > 31 ? 31 : y0);
  int y1c = (y0 + 1) < 0 ? 0 : ((y0 + 1) > 31 ? 31 : (y0 + 1));
  const float* sb = scores + (b << 10);
  float v00 = sb[y0c * 32 + x0c], v01 = sb[y0c * 32 + x1c];
  float v10 = sb[y1c * 32 + x0c], v11 = sb[y1c * 32 + x1c];
  float v0 = v00 + (v01 - v00) * fx;
  float v1 = v10 + (v11 - v10) * fx;
  out[idx] = v0 + (v1 - v0) * fy;
}

extern "C" void kernel_launch(void* const* d_in, const int* in_sizes, int n_in,
                              void* d_out, int out_size, void* d_ws, size_t ws_size,
                              hipStream_t stream) {
  const float* emb  = (const float*)d_in[0];   // [4,128,32,32]
  const float* bank = (const float*)d_in[1];   // [50000,128]
  float* out = (float*)d_out;                  // [4,1,512,512]
  char* ws = (char*)d_ws;

  u16*   bankbf = (u16*)(ws + WS_BANKBF);
  float* b2     = (float*)(ws + WS_B2);
  u16*   qbf    = (u16*)(ws + WS_QBF);
  float* q2     = (float*)(ws + WS_Q2);
  float* segd   = (float*)(ws + WS_SEGD);
  float* scores = (float*)(ws + WS_SCORES);

  prep_bank<<<NPAD / 8, 256, 0, stream>>>(bank, bankbf, b2);
  prep_q<<<NQ / 256, 256, 0, stream>>>(emb, qbf, q2);
  knn_kernel<<<16 * SEGS, 512, 0, stream>>>(bankbf, b2, qbf, segd);
  final_merge<<<NQ / 256, 256, 0, stream>>>(segd, q2, scores);
  resize_kernel<<<(NQ * 256) / 256, 256, 0, stream>>>(scores, out);
}